// Round 11
// baseline (3040.704 us; speedup 1.0000x reference)
//
#include <hip/hip_runtime.h>
#include <math.h>

#define B_  1024
#define T_  512
#define D_  30
#define H1_ 96
#define G1_ 384
#define H2_ 64
#define G2_ 256

// Inter-kernel buffers as device globals (.bss, bound at module load).
__device__ float g_h1[(size_t)B_ * T_ * 192];   // 384 MiB: layer-1 output
__device__ float g_h2f[(size_t)B_ * H2_];       // layer-2 fwd final state

__device__ __forceinline__ float fast_tanh(float v) {
  float a = fabsf(v);
  float e = __expf(-2.0f * a);
  float t = 1.0f - 2.0f * e / (1.0f + e);
  return v < 0.0f ? -t : t;
}
__device__ __forceinline__ float fast_sigmoid(float v) {
  return 0.5f + 0.5f * fast_tanh(0.5f * v);   // exact identity, overflow-safe
}

#define FMAROW(a_, w_, v_)                                                    \
  a_ = fmaf(w_.x, v_.x, a_); a_ = fmaf(w_.y, v_.y, a_);                       \
  a_ = fmaf(w_.z, v_.z, a_); a_ = fmaf(w_.w, v_.w, a_);

// Barrier with LDS-only drain (skips vmcnt: global stores + prefetches stay
// in flight across steps).
#define BAR_LGKM() do {                                                       \
    asm volatile("s_waitcnt lgkmcnt(0)" ::: "memory");                        \
    __builtin_amdgcn_s_barrier();                                             \
    asm volatile("" ::: "memory");                                            \
  } while (0)

// ---------------------------------------------------------------------------
// Layer 1: bidirectional LSTM over x (B,T,30) -> g_h1 (B,T,192)
// grid (256, 2): FOUR-batch tile -> 512 blocks. This is the R8 kernel body
// VERBATIM (correctness-proven: R8 passed, absmax 0) with ONE change:
// __launch_bounds__(768, 4) instead of (768, 6).
//   R8 post-mortem: the (768,6) 85-VGPR cap spilled the 64-float weight set
//   (VGPR=40, 49 GB scratch FETCH, 13 ms). R9 measured the same weight-set +
//   shfl structure at VGPR=64 under (768,4) -- exactly the 8-waves/SIMD
//   boundary (m69). A 12-wave block at VGPR<=64 + 4.4 KB LDS leaves room for
//   TWO co-resident blocks/CU (24 waves <= 32): block B's FMA phase fills
//   block A's barrier/reduce stall (the ~5000 cyc/step phase-serialization
//   identified in R9's cycle model).
// Thread = (unit j 0..95 owning gate rows j,j+96,j+192,j+288; chunk e 0..7
// of 16 k). Slot k of lane e accumulates batch (e&3)^k (4-batch tile);
// shfl_xor butterfly rounds xor1 {s0+=s1, s2+=s3}, xor2 {s0+=s2},
// xor4 self-add -> slot0 = full-K sum of batch e&3 in every lane; lanes
// e<4 write cell (j, batch e). One barrier/step.
// hx [2 buf][8 chunks][4 b * 16 + 4 pad = 68].
// v[128]: chunks 0-1 = x_t (30 + 2 zero-pad), chunks 2-7 = h_{t-1}.
// ---------------------------------------------------------------------------
__global__ __launch_bounds__(768, 4)
void lstm1_kernel(const float* __restrict__ x,
                  const float* __restrict__ Wih_f, const float* __restrict__ Whh_f,
                  const float* __restrict__ bih_f, const float* __restrict__ bhh_f,
                  const float* __restrict__ Wih_b, const float* __restrict__ Whh_b,
                  const float* __restrict__ bih_b, const float* __restrict__ bhh_b)
{
  const int tid = threadIdx.x;
  const int dir = blockIdx.y;
  const int b0  = blockIdx.x * 4;

  const float* __restrict__ Wih = dir ? Wih_b : Wih_f;
  const float* __restrict__ Whh = dir ? Whh_b : Whh_f;
  const float* __restrict__ bih = dir ? bih_b : bih_f;
  const float* __restrict__ bhh = dir ? bhh_b : bhh_f;

  const int j  = tid >> 3;                       // unit 0..95
  const int e  = tid & 7;                        // k-chunk 0..7 (16 k each)

  __shared__ __align__(16) float hxs[2 * 544];   // [2][8 c][68]  (4.35 KB)

  // 16 NAMED float4 regs: 4 gate rows x 4 float4 over k in [16e, 16e+16).
  float4 wA0,wA1,wA2,wA3, wB0,wB1,wB2,wB3, wC0,wC1,wC2,wC3, wD0,wD1,wD2,wD3;
  if (e < 2) {                                   // k = 0..31: x-part (30 + 2 pad)
    const int k0 = e * 16;
#define LDXF(r_, kk) (((kk) < D_) ? Wih[(r_) * D_ + (kk)] : 0.0f)
#define LW4(d0,d1,d2,d3, r_) {                                                \
    d0 = make_float4(LDXF(r_,k0+ 0),LDXF(r_,k0+ 1),LDXF(r_,k0+ 2),LDXF(r_,k0+ 3)); \
    d1 = make_float4(LDXF(r_,k0+ 4),LDXF(r_,k0+ 5),LDXF(r_,k0+ 6),LDXF(r_,k0+ 7)); \
    d2 = make_float4(LDXF(r_,k0+ 8),LDXF(r_,k0+ 9),LDXF(r_,k0+10),LDXF(r_,k0+11)); \
    d3 = make_float4(LDXF(r_,k0+12),LDXF(r_,k0+13),LDXF(r_,k0+14),LDXF(r_,k0+15)); }
    LW4(wA0,wA1,wA2,wA3, j      )
    LW4(wB0,wB1,wB2,wB3, j +  96)
    LW4(wC0,wC1,wC2,wC3, j + 192)
    LW4(wD0,wD1,wD2,wD3, j + 288)
#undef LW4
#undef LDXF
  } else {                                       // k = 16e..16e+15: h-part
    const int c0 = e * 16 - 32;
    const float4* pA = (const float4*)(Whh + (j      ) * H1_ + c0);
    const float4* pB = (const float4*)(Whh + (j +  96) * H1_ + c0);
    const float4* pC = (const float4*)(Whh + (j + 192) * H1_ + c0);
    const float4* pD = (const float4*)(Whh + (j + 288) * H1_ + c0);
    wA0=pA[0]; wA1=pA[1]; wA2=pA[2]; wA3=pA[3];
    wB0=pB[0]; wB1=pB[1]; wB2=pB[2]; wB3=pB[3];
    wC0=pC[0]; wC1=pC[1]; wC2=pC[2]; wC3=pC[3];
    wD0=pD[0]; wD1=pD[1]; wD2=pD[2]; wD3=pD[3];
  }

  const float bias_i = bih[j      ] + bhh[j      ];
  const float bias_f = bih[j +  96] + bhh[j +  96];
  const float bias_g = bih[j + 192] + bhh[j + 192];
  const float bias_o = bih[j + 288] + bhh[j + 288];
  float c_state = 0.0f;                          // cell (j, batch e&3), 2x dup

  for (int i = tid; i < 2 * 544; i += 768) hxs[i] = 0.0f;
  __syncthreads();
  const int xb = tid / 30;                       // x stagers: tid < 120
  const int xd = tid - xb * 30;
  const int xoff = 68 * (xd >> 4) + 16 * xb + (xd & 15);
  if (tid < 120) {
    const int t0 = dir ? (T_ - 1) : 0;
    hxs[xoff] = x[((size_t)(b0 + xb) * T_ + t0) * D_ + xd];
  }
  __syncthreads();

  // slot k reads (chunk e, batch (e&3)^k): f4 index = 17e + 4*((e&3)^k)
  const int vo0 = 17 * e + 4 * ((e & 3) ^ 0);
  const int vo1 = 17 * e + 4 * ((e & 3) ^ 1);
  const int vo2 = 17 * e + 4 * ((e & 3) ^ 2);
  const int vo3 = 17 * e + 4 * ((e & 3) ^ 3);
  const int hoff = 68 * (2 + (j >> 4)) + 16 * (e & 3) + (j & 15);
  float* __restrict__ gp = g_h1 + ((size_t)(b0 + (e & 3)) * T_) * 192
                                + (size_t)dir * 96 + j;

  for (int s = 0; s < T_; ++s) {
    const int t   = dir ? (T_ - 1 - s) : s;
    const int cur = s & 1, nxt = cur ^ 1;
    float xn = 0.0f;
    if (tid < 120 && s + 1 < T_) {
      const int tn = dir ? (t - 1) : (t + 1);
      xn = x[((size_t)(b0 + xb) * T_ + tn) * D_ + xd];
    }
    const float4* hb = (const float4*)(hxs + cur * 544);
    float aI0=0.f,aI1=0.f,aI2=0.f,aI3=0.f;
    float aF0=0.f,aF1=0.f,aF2=0.f,aF3=0.f;
    float aG0=0.f,aG1=0.f,aG2=0.f,aG3=0.f;
    float aO0=0.f,aO1=0.f,aO2=0.f,aO3=0.f;
#define FB1(i) {                                                              \
    float4 v0 = hb[vo0 + i]; float4 v1 = hb[vo1 + i];                         \
    float4 v2 = hb[vo2 + i]; float4 v3 = hb[vo3 + i];                         \
    FMAROW(aI0, wA##i, v0) FMAROW(aF0, wB##i, v0)                             \
    FMAROW(aG0, wC##i, v0) FMAROW(aO0, wD##i, v0)                             \
    FMAROW(aI1, wA##i, v1) FMAROW(aF1, wB##i, v1)                             \
    FMAROW(aG1, wC##i, v1) FMAROW(aO1, wD##i, v1)                             \
    FMAROW(aI2, wA##i, v2) FMAROW(aF2, wB##i, v2)                             \
    FMAROW(aG2, wC##i, v2) FMAROW(aO2, wD##i, v2)                             \
    FMAROW(aI3, wA##i, v3) FMAROW(aF3, wB##i, v3)                             \
    FMAROW(aG3, wC##i, v3) FMAROW(aO3, wD##i, v3) }
    FB1(0) FB1(1) FB1(2) FB1(3)
#undef FB1
    // shfl_xor butterfly (R8-verified): slot s of lane e = batch (e&3)^s.
    // xor1 merges s0/s1 and s2/s3; xor2 merges s0/s2; xor4 self-add
    // completes the 8 chunks. Slot0 = full sum of batch e&3 in every lane.
    aI0 += __shfl_xor(aI1, 1); aI2 += __shfl_xor(aI3, 1);
    aF0 += __shfl_xor(aF1, 1); aF2 += __shfl_xor(aF3, 1);
    aG0 += __shfl_xor(aG1, 1); aG2 += __shfl_xor(aG3, 1);
    aO0 += __shfl_xor(aO1, 1); aO2 += __shfl_xor(aO3, 1);
    aI0 += __shfl_xor(aI2, 2); aF0 += __shfl_xor(aF2, 2);
    aG0 += __shfl_xor(aG2, 2); aO0 += __shfl_xor(aO2, 2);
    aI0 += __shfl_xor(aI0, 4); aF0 += __shfl_xor(aF0, 4);
    aG0 += __shfl_xor(aG0, 4); aO0 += __shfl_xor(aO0, 4);
    {
      float gi = aI0 + bias_i;
      float gf = aF0 + bias_f;
      float gg = aG0 + bias_g;
      float go = aO0 + bias_o;
      float iv = fast_sigmoid(gi);
      float fv = fast_sigmoid(gf);
      float ov = fast_sigmoid(go);
      c_state = fv * c_state + iv * fast_tanh(gg);
      float h = ov * fast_tanh(c_state);
      if (e < 4) {                               // one writer per (j, batch e)
        hxs[nxt * 544 + hoff] = h;
        gp[(size_t)t * 192] = h;
      }
    }
    if (tid < 120 && s + 1 < T_) hxs[nxt * 544 + xoff] = xn;
    BAR_LGKM();
  }
}

// ---------------------------------------------------------------------------
// Layer 2 forward scan: g_h1 (B,T,192) -> g_h2f (B,64).  [R6 structure: best
// measured ~790us.]
// grid 256: 4 batch/block. 1024 threads = (gate-PAIR jj = tid%128 owning rows
// jj and jj+128, k-eighth e = tid/128). gbuf stride 33 (measured clean).
// v[256]: [0:192)=h1_t, [192:256)=h2_{t-1}. Barriers: BAR_LGKM.
// ---------------------------------------------------------------------------
__global__ __launch_bounds__(1024, 4)
void lstm2f_kernel(const float* __restrict__ Wih, const float* __restrict__ Whh,
                   const float* __restrict__ bih, const float* __restrict__ bhh)
{
  const int tid = threadIdx.x;
  const int b0  = blockIdx.x * 4;
  const int jj  = tid % 128;                     // pair rows jj, jj+128
  const int e   = tid / 128;                     // k-eighth (wave-uniform)

  __shared__ __align__(16) float hx[4][256];     // [b][0:192 h1 | 192:256 h2prev]
  __shared__ float gbuf[G2_ * 33];               // [row][b*8+e], stride 33

  float4 w0,w1,w2,w3,w4,w5,w6,w7,w8,w9,w10,w11,w12,w13,w14,w15;
  {
    const float4* wa = (e < 6) ? (const float4*)(Wih + jj * 192 + 32 * e)
                               : (const float4*)(Whh + jj * H2_ + 32 * (e - 6));
    w0 = wa[0];  w1 = wa[1];  w2 = wa[2];  w3 = wa[3];
    w4 = wa[4];  w5 = wa[5];  w6 = wa[6];  w7 = wa[7];
    const float4* wb = (e < 6) ? (const float4*)(Wih + (jj + 128) * 192 + 32 * e)
                               : (const float4*)(Whh + (jj + 128) * H2_ + 32 * (e - 6));
    w8  = wb[0]; w9  = wb[1]; w10 = wb[2]; w11 = wb[3];
    w12 = wb[4]; w13 = wb[5]; w14 = wb[6]; w15 = wb[7];
  }

  const int uj = tid & 63;                       // updaters: tid < 256
  const int ub = (tid >> 6) & 3;
  const float bias_i = bih[uj      ] + bhh[uj      ];
  const float bias_f = bih[uj +  64] + bhh[uj +  64];
  const float bias_g = bih[uj + 128] + bhh[uj + 128];
  const float bias_o = bih[uj + 192] + bhh[uj + 192];
  float c_state = 0.0f;

  for (int i = tid; i < 4 * 256; i += 1024) (&hx[0][0])[i] = 0.0f;
  __syncthreads();
  const int pb = tid / 96;                       // h1 stagers: tid < 384
  const int pj = tid - pb * 96;
  if (tid < 384) {
    *(float2*)&hx[pb][pj * 2] =
        *(const float2*)&g_h1[((size_t)(b0 + pb) * T_ + 0) * 192 + pj * 2];
  }
  __syncthreads();

  const int eoff = e * 8;
  const float4* hx4 = (const float4*)(&hx[0][0]);

  for (int s = 0; s < T_; ++s) {
    float2 pre = make_float2(0.0f, 0.0f);
    if (tid < 384 && s + 1 < T_) {
      pre = *(const float2*)&g_h1[((size_t)(b0 + pb) * T_ + (s + 1)) * 192 + pj * 2];
    }
    float accA0=0.f, accA1=0.f, accA2=0.f, accA3=0.f;
    float accB0=0.f, accB1=0.f, accB2=0.f, accB3=0.f;
#define FB2(i, k) {                                                           \
    float4 v0 = hx4[0*64 + eoff + i]; float4 v1 = hx4[1*64 + eoff + i];       \
    float4 v2 = hx4[2*64 + eoff + i]; float4 v3 = hx4[3*64 + eoff + i];       \
    FMAROW(accA0, w##i, v0) FMAROW(accB0, w##k, v0)                           \
    FMAROW(accA1, w##i, v1) FMAROW(accB1, w##k, v1)                           \
    FMAROW(accA2, w##i, v2) FMAROW(accB2, w##k, v2)                           \
    FMAROW(accA3, w##i, v3) FMAROW(accB3, w##k, v3) }
    FB2(0,8) FB2(1,9) FB2(2,10) FB2(3,11)
    FB2(4,12) FB2(5,13) FB2(6,14) FB2(7,15)
#undef FB2
    {
      const int ga = jj * 33 + e;                // lanes: jj consecutive -> 2-way
      gbuf[ga +  0] = accA0; gbuf[ga +  8] = accA1;
      gbuf[ga + 16] = accA2; gbuf[ga + 24] = accA3;
      const int gbB = (jj + 128) * 33 + e;
      gbuf[gbB +  0] = accB0; gbuf[gbB +  8] = accB1;
      gbuf[gbB + 16] = accB2; gbuf[gbB + 24] = accB3;
    }
    BAR_LGKM();
    if (tid < 384 && s + 1 < T_) *(float2*)&hx[pb][pj * 2] = pre;
    if (tid < 256) {
      const int ro = ub * 8;
      float gi = bias_i, gf = bias_f, gg = bias_g, go = bias_o;
#pragma unroll
      for (int ee = 0; ee < 8; ++ee) {
        gi += gbuf[(uj      ) * 33 + ro + ee];
        gf += gbuf[(uj +  64) * 33 + ro + ee];
        gg += gbuf[(uj + 128) * 33 + ro + ee];
        go += gbuf[(uj + 192) * 33 + ro + ee];
      }
      float iv = fast_sigmoid(gi), fv = fast_sigmoid(gf), ov = fast_sigmoid(go);
      c_state = fv * c_state + iv * fast_tanh(gg);
      float h = ov * fast_tanh(c_state);
      hx[ub][192 + uj] = h;
      if (s == T_ - 1) g_h2f[(b0 + ub) * H2_ + uj] = h;
    }
    BAR_LGKM();
  }
}

// ---------------------------------------------------------------------------
// Tail: layer-2 backward (ONE step from zero state on h1[:,T-1,:]) + dense
// head. grid 128 x 256 threads, 8 batch/block. (negligible runtime)
// ---------------------------------------------------------------------------
__global__ __launch_bounds__(256)
void tail_kernel(const float* __restrict__ Wih, const float* __restrict__ bih,
                 const float* __restrict__ bhh,
                 const float* __restrict__ W1, const float* __restrict__ b1,
                 const float* __restrict__ W2, const float* __restrict__ b2,
                 float* __restrict__ out)
{
  const int tid = threadIdx.x;
  const int b0  = blockIdx.x * 8;

  __shared__ __align__(16) float hl[8][192];    // h1 at t = T-1
  __shared__ float gb[G2_ * 9];
  __shared__ __align__(16) float last[8][128];  // [h2f | h2b]
  __shared__ float db[8][32];

  for (int i = tid; i < 8 * 96; i += 256) {
    int bb = i / 96, jj = i - (i / 96) * 96;
    *(float2*)&hl[bb][jj * 2] =
        *(const float2*)&g_h1[((size_t)(b0 + bb) * T_ + (T_ - 1)) * 192 + jj * 2];
  }
  for (int i = tid; i < 8 * 64; i += 256) {
    int bb = i >> 6, jj = i & 63;
    last[bb][jj] = g_h2f[(b0 + bb) * H2_ + jj];
  }
  __syncthreads();

  {
    const int gg_ = tid;
    const float* wr = Wih + gg_ * 192;
    const float bias = bih[gg_] + bhh[gg_];
    float acc[8];
#pragma unroll
    for (int b = 0; b < 8; ++b) acc[b] = bias;
#pragma unroll 4
    for (int qq = 0; qq < 48; ++qq) {
      float4 wv = *(const float4*)&wr[qq * 4];
#pragma unroll
      for (int b = 0; b < 8; ++b) {
        float4 v = *(const float4*)&hl[b][qq * 4];
        acc[b] = fmaf(wv.x, v.x, acc[b]);
        acc[b] = fmaf(wv.y, v.y, acc[b]);
        acc[b] = fmaf(wv.z, v.z, acc[b]);
        acc[b] = fmaf(wv.w, v.w, acc[b]);
      }
    }
#pragma unroll
    for (int b = 0; b < 8; ++b) gb[gg_ * 9 + b] = acc[b];
  }
  __syncthreads();

  for (int p = tid; p < 512; p += 256) {
    int jj = p & 63, bb = p >> 6;
    float gi = gb[(jj      ) * 9 + bb];
    float gg = gb[(jj + 128) * 9 + bb];
    float go = gb[(jj + 192) * 9 + bb];
    float c  = fast_sigmoid(gi) * fast_tanh(gg);
    float h  = fast_sigmoid(go) * fast_tanh(c);
    last[bb][64 + jj] = h;
  }
  __syncthreads();

  {
    int uu = tid & 31, bb = tid >> 5;
    const float* wr1 = W1 + uu * 128;
    float a = b1[uu];
#pragma unroll
    for (int qq = 0; qq < 32; ++qq) {
      float4 wv = *(const float4*)&wr1[qq * 4];
      float4 v  = *(const float4*)&last[bb][qq * 4];
      a = fmaf(wv.x, v.x, a); a = fmaf(wv.y, v.y, a);
      a = fmaf(wv.z, v.z, a); a = fmaf(wv.w, v.w, a);
    }
    db[bb][uu] = fmaxf(a, 0.0f);
  }
  __syncthreads();

  if (tid < 8) {
    float a = b2[0];
#pragma unroll
    for (int u2 = 0; u2 < 32; ++u2) a = fmaf(db[tid][u2], W2[u2], a);
    out[b0 + tid] = a;
  }
}

extern "C" void kernel_launch(void* const* d_in, const int* in_sizes, int n_in,
                              void* d_out, int out_size, void* d_ws, size_t ws_size,
                              hipStream_t stream)
{
  const float* x     = (const float*)d_in[0];
  const float* Wih1f = (const float*)d_in[1];
  const float* Whh1f = (const float*)d_in[2];
  const float* bih1f = (const float*)d_in[3];
  const float* bhh1f = (const float*)d_in[4];
  const float* Wih1b = (const float*)d_in[5];
  const float* Whh1b = (const float*)d_in[6];
  const float* bih1b = (const float*)d_in[7];
  const float* bhh1b = (const float*)d_in[8];
  const float* Wih2f = (const float*)d_in[9];
  const float* Whh2f = (const float*)d_in[10];
  const float* bih2f = (const float*)d_in[11];
  const float* bhh2f = (const float*)d_in[12];
  const float* Wih2b = (const float*)d_in[13];
  /* Whh2b (d_in[14]) unused: layer-2 backward at t=T-1 is one step from h=0 */
  const float* bih2b = (const float*)d_in[15];
  const float* bhh2b = (const float*)d_in[16];
  const float* W1    = (const float*)d_in[17];
  const float* b1    = (const float*)d_in[18];
  const float* W2    = (const float*)d_in[19];
  const float* b2    = (const float*)d_in[20];

  (void)d_ws; (void)ws_size; (void)in_sizes; (void)n_in; (void)out_size;

  lstm1_kernel<<<dim3(256, 2), 768, 0, stream>>>(
      x, Wih1f, Whh1f, bih1f, bhh1f, Wih1b, Whh1b, bih1b, bhh1b);
  lstm2f_kernel<<<256, 1024, 0, stream>>>(
      Wih2f, Whh2f, bih2f, bhh2f);
  tail_kernel<<<128, 256, 0, stream>>>(
      Wih2b, bih2b, bhh2b, W1, b1, W2, b2, (float*)d_out);
}

// Round 12
// 2758.680 us; speedup vs baseline: 1.1022x; 1.1022x over previous
//
#include <hip/hip_runtime.h>
#include <math.h>

#define B_  1024
#define T_  512
#define D_  30
#define H1_ 96
#define G1_ 384
#define H2_ 64
#define G2_ 256

// Inter-kernel buffers as device globals (.bss, bound at module load).
__device__ float g_h1[(size_t)B_ * T_ * 192];   // 384 MiB: layer-1 output
__device__ float g_h2f[(size_t)B_ * H2_];       // layer-2 fwd final state

__device__ __forceinline__ float fast_tanh(float v) {
  float a = fabsf(v);
  float e = __expf(-2.0f * a);
  float t = 1.0f - 2.0f * e / (1.0f + e);
  return v < 0.0f ? -t : t;
}
__device__ __forceinline__ float fast_sigmoid(float v) {
  return 0.5f + 0.5f * fast_tanh(0.5f * v);   // exact identity, overflow-safe
}

#define FMAROW(a_, w_, v_)                                                    \
  a_ = fmaf(w_.x, v_.x, a_); a_ = fmaf(w_.y, v_.y, a_);                       \
  a_ = fmaf(w_.z, v_.z, a_); a_ = fmaf(w_.w, v_.w, a_);

// Barrier with LDS-only drain (skips vmcnt: global stores + prefetches stay
// in flight across steps).
#define BAR_LGKM() do {                                                       \
    asm volatile("s_waitcnt lgkmcnt(0)" ::: "memory");                        \
    __builtin_amdgcn_s_barrier();                                             \
    asm volatile("" ::: "memory");                                            \
  } while (0)

// ---------------------------------------------------------------------------
// Layer 1 (R5 variant -- best measured: 1886 us). Bidirectional LSTM over
// x (B,T,30) -> g_h1 (B,T,192). grid (128, 2): 8-batch tile, dir.
// 768 threads, tid = j*8 + e (j = unit 0..95 owning gate rows j,j+96,j+192,
// j+288; e = k-chunk 0..7 of 16 k). All 8 chunk-partials of a unit live in
// ONE wave -> reduction is wave-internal (f4 LDS scratch, no extra barrier);
// ONE block barrier per step. Every lane is a cell-updater (96x8 = 768).
// NOTE: this layout shows 1.1e8 SQ_LDS_BANK_CONFLICT but is the FASTEST
// measured lstm1 (R5 1886 vs R6 bank-clean-scalar 1920 vs R9 shfl 2015):
// trading the conflicts for more issue ops or shfl latency is net-negative.
// Closed levers (measured): 2 blocks/CU impossible without spilling the
// 64-float weight set (R8: VGPR cap 85 -> 49 GB scratch; R11: AGPR-parked
// total ~128 regs -> 16-wave ceiling); reduce-impl variants equal +-5%.
// v[128]: chunks 0-1 = x_t (30 + 2 zero-pad), chunks 2-7 = h_{t-1}.
// ---------------------------------------------------------------------------
__global__ __launch_bounds__(768, 4)
void lstm1_kernel(const float* __restrict__ x,
                  const float* __restrict__ Wih_f, const float* __restrict__ Whh_f,
                  const float* __restrict__ bih_f, const float* __restrict__ bhh_f,
                  const float* __restrict__ Wih_b, const float* __restrict__ Whh_b,
                  const float* __restrict__ bih_b, const float* __restrict__ bhh_b)
{
  const int tid = threadIdx.x;
  const int dir = blockIdx.y;
  const int b0  = blockIdx.x * 8;

  const float* __restrict__ Wih = dir ? Wih_b : Wih_f;
  const float* __restrict__ Whh = dir ? Whh_b : Whh_f;
  const float* __restrict__ bih = dir ? bih_b : bih_f;
  const float* __restrict__ bhh = dir ? bhh_b : bhh_f;

  const int j  = tid >> 3;                       // unit 0..95
  const int e  = tid & 7;                        // k-chunk 0..7
  const int wv = tid >> 6;                       // wave 0..11
  const int jl = j & 7;                          // unit-in-wave 0..7

  // hx: [2 buf][8 chunks][8 b * 16 + 4 pad = 132]  (8.4 KB)
  __shared__ __align__(16) float hxs[2 * 1056];
  // scratch: per-wave [8 jl][8 i(batch)][8 e'] f4, strides 73/9/1
  __shared__ float4 scr4[12 * 584];              // 112.1 KB

  // 16 NAMED float4 regs: 4 gate rows x 4 float4 over k in [16e, 16e+16).
  float4 wA0,wA1,wA2,wA3, wB0,wB1,wB2,wB3, wC0,wC1,wC2,wC3, wD0,wD1,wD2,wD3;
  if (e < 2) {                                   // k = 0..31: x-part (30 + 2 pad)
    const int k0 = e * 16;
#define LDXF(r_, kk) (((kk) < D_) ? Wih[(r_) * D_ + (kk)] : 0.0f)
#define LW4(d0,d1,d2,d3, r_) {                                                \
    d0 = make_float4(LDXF(r_,k0+ 0),LDXF(r_,k0+ 1),LDXF(r_,k0+ 2),LDXF(r_,k0+ 3)); \
    d1 = make_float4(LDXF(r_,k0+ 4),LDXF(r_,k0+ 5),LDXF(r_,k0+ 6),LDXF(r_,k0+ 7)); \
    d2 = make_float4(LDXF(r_,k0+ 8),LDXF(r_,k0+ 9),LDXF(r_,k0+10),LDXF(r_,k0+11)); \
    d3 = make_float4(LDXF(r_,k0+12),LDXF(r_,k0+13),LDXF(r_,k0+14),LDXF(r_,k0+15)); }
    LW4(wA0,wA1,wA2,wA3, j      )
    LW4(wB0,wB1,wB2,wB3, j +  96)
    LW4(wC0,wC1,wC2,wC3, j + 192)
    LW4(wD0,wD1,wD2,wD3, j + 288)
#undef LW4
#undef LDXF
  } else {                                       // k = 16e..16e+15: h-part
    const int c0 = e * 16 - 32;
    const float4* pA = (const float4*)(Whh + (j      ) * H1_ + c0);
    const float4* pB = (const float4*)(Whh + (j +  96) * H1_ + c0);
    const float4* pC = (const float4*)(Whh + (j + 192) * H1_ + c0);
    const float4* pD = (const float4*)(Whh + (j + 288) * H1_ + c0);
    wA0=pA[0]; wA1=pA[1]; wA2=pA[2]; wA3=pA[3];
    wB0=pB[0]; wB1=pB[1]; wB2=pB[2]; wB3=pB[3];
    wC0=pC[0]; wC1=pC[1]; wC2=pC[2]; wC3=pC[3];
    wD0=pD[0]; wD1=pD[1]; wD2=pD[2]; wD3=pD[3];
  }

  const float bias_i = bih[j      ] + bhh[j      ];
  const float bias_f = bih[j +  96] + bhh[j +  96];
  const float bias_g = bih[j + 192] + bhh[j + 192];
  const float bias_o = bih[j + 288] + bhh[j + 288];
  float c_state = 0.0f;

  for (int i = tid; i < 2 * 1056; i += 768) hxs[i] = 0.0f;
  __syncthreads();
  const int xb = tid / 30;                       // x stagers: tid < 240
  const int xd = tid - xb * 30;
  const int xoff = 132 * (xd >> 4) + 16 * xb + (xd & 15);
  if (tid < 240) {
    const int t0 = dir ? (T_ - 1) : 0;
    hxs[xoff] = x[((size_t)(b0 + xb) * T_ + t0) * D_ + xd];
  }
  __syncthreads();

  const int ef = 33 * e;                         // f4 base of my k-chunk
  float4* swp = scr4 + wv * 584 + jl * 73 + e;       // writer base: [i*9]
  const float4* srd = scr4 + wv * 584 + jl * 73 + e * 9;  // reader: [k]
  const int hoff = 132 * (2 + (j >> 4)) + 16 * e + ((32 + j) & 15);
  float* __restrict__ gp = g_h1 + ((size_t)(b0 + e) * T_) * 192
                                + (size_t)dir * 96 + j;

  for (int s = 0; s < T_; ++s) {
    const int t   = dir ? (T_ - 1 - s) : s;
    const int cur = s & 1, nxt = cur ^ 1;
    float xn = 0.0f;
    if (tid < 240 && s + 1 < T_) {
      const int tn = dir ? (t - 1) : (t + 1);
      xn = x[((size_t)(b0 + xb) * T_ + tn) * D_ + xd];
    }
    const float4* hb = (const float4*)(hxs + cur * 1056);
    float aI0=0.f,aI1=0.f,aI2=0.f,aI3=0.f,aI4=0.f,aI5=0.f,aI6=0.f,aI7=0.f;
    float aF0=0.f,aF1=0.f,aF2=0.f,aF3=0.f,aF4=0.f,aF5=0.f,aF6=0.f,aF7=0.f;
    float aG0=0.f,aG1=0.f,aG2=0.f,aG3=0.f,aG4=0.f,aG5=0.f,aG6=0.f,aG7=0.f;
    float aO0=0.f,aO1=0.f,aO2=0.f,aO3=0.f,aO4=0.f,aO5=0.f,aO6=0.f,aO7=0.f;
#define FB1(i) {                                                              \
    float4 v0 = hb[ef +  0 + i]; float4 v1 = hb[ef +  4 + i];                 \
    float4 v2 = hb[ef +  8 + i]; float4 v3 = hb[ef + 12 + i];                 \
    float4 v4 = hb[ef + 16 + i]; float4 v5 = hb[ef + 20 + i];                 \
    float4 v6 = hb[ef + 24 + i]; float4 v7 = hb[ef + 28 + i];                 \
    FMAROW(aI0, wA##i, v0) FMAROW(aF0, wB##i, v0)                             \
    FMAROW(aG0, wC##i, v0) FMAROW(aO0, wD##i, v0)                             \
    FMAROW(aI1, wA##i, v1) FMAROW(aF1, wB##i, v1)                             \
    FMAROW(aG1, wC##i, v1) FMAROW(aO1, wD##i, v1)                             \
    FMAROW(aI2, wA##i, v2) FMAROW(aF2, wB##i, v2)                             \
    FMAROW(aG2, wC##i, v2) FMAROW(aO2, wD##i, v2)                             \
    FMAROW(aI3, wA##i, v3) FMAROW(aF3, wB##i, v3)                             \
    FMAROW(aG3, wC##i, v3) FMAROW(aO3, wD##i, v3)                             \
    FMAROW(aI4, wA##i, v4) FMAROW(aF4, wB##i, v4)                             \
    FMAROW(aG4, wC##i, v4) FMAROW(aO4, wD##i, v4)                             \
    FMAROW(aI5, wA##i, v5) FMAROW(aF5, wB##i, v5)                             \
    FMAROW(aG5, wC##i, v5) FMAROW(aO5, wD##i, v5)                             \
    FMAROW(aI6, wA##i, v6) FMAROW(aF6, wB##i, v6)                             \
    FMAROW(aG6, wC##i, v6) FMAROW(aO6, wD##i, v6)                             \
    FMAROW(aI7, wA##i, v7) FMAROW(aF7, wB##i, v7)                             \
    FMAROW(aG7, wC##i, v7) FMAROW(aO7, wD##i, v7) }
    FB1(0) FB1(1) FB1(2) FB1(3)
#undef FB1
    // wave-internal reduction: write my 8 batch-partials ([i*9]), read my
    // batch's 8 chunk-partials ([k]). Same wave -> no barrier needed.
    swp[0*9] = make_float4(aI0, aF0, aG0, aO0);
    swp[1*9] = make_float4(aI1, aF1, aG1, aO1);
    swp[2*9] = make_float4(aI2, aF2, aG2, aO2);
    swp[3*9] = make_float4(aI3, aF3, aG3, aO3);
    swp[4*9] = make_float4(aI4, aF4, aG4, aO4);
    swp[5*9] = make_float4(aI5, aF5, aG5, aO5);
    swp[6*9] = make_float4(aI6, aF6, aG6, aO6);
    swp[7*9] = make_float4(aI7, aF7, aG7, aO7);
    {
      float4 r0 = srd[0], r1 = srd[1], r2 = srd[2], r3 = srd[3];
      float4 r4 = srd[4], r5 = srd[5], r6 = srd[6], r7 = srd[7];
      float gi = bias_i + r0.x + r1.x + r2.x + r3.x + r4.x + r5.x + r6.x + r7.x;
      float gf = bias_f + r0.y + r1.y + r2.y + r3.y + r4.y + r5.y + r6.y + r7.y;
      float gg = bias_g + r0.z + r1.z + r2.z + r3.z + r4.z + r5.z + r6.z + r7.z;
      float go = bias_o + r0.w + r1.w + r2.w + r3.w + r4.w + r5.w + r6.w + r7.w;
      float iv = fast_sigmoid(gi);
      float fv = fast_sigmoid(gf);
      float ov = fast_sigmoid(go);
      c_state = fv * c_state + iv * fast_tanh(gg);
      float h = ov * fast_tanh(c_state);
      hxs[nxt * 1056 + hoff] = h;                // my cell = (unit j, batch e)
      gp[(size_t)t * 192] = h;
    }
    if (tid < 240 && s + 1 < T_) hxs[nxt * 1056 + xoff] = xn;
    BAR_LGKM();
  }
}

// ---------------------------------------------------------------------------
// Layer 2 forward scan (R6 variant -- best measured: ~790 us).
// g_h1 (B,T,192) -> g_h2f (B,64). grid 256: 4 batch/block. 1024 threads =
// (gate-PAIR jj = tid%128 owning rows jj and jj+128, k-eighth e = tid/128).
// gbuf stride 33 (measured clean). v[256]: [0:192)=h1_t, [192:256)=h2_{t-1}.
// ---------------------------------------------------------------------------
__global__ __launch_bounds__(1024, 4)
void lstm2f_kernel(const float* __restrict__ Wih, const float* __restrict__ Whh,
                   const float* __restrict__ bih, const float* __restrict__ bhh)
{
  const int tid = threadIdx.x;
  const int b0  = blockIdx.x * 4;
  const int jj  = tid % 128;                     // pair rows jj, jj+128
  const int e   = tid / 128;                     // k-eighth (wave-uniform)

  __shared__ __align__(16) float hx[4][256];     // [b][0:192 h1 | 192:256 h2prev]
  __shared__ float gbuf[G2_ * 33];               // [row][b*8+e], stride 33

  float4 w0,w1,w2,w3,w4,w5,w6,w7,w8,w9,w10,w11,w12,w13,w14,w15;
  {
    const float4* wa = (e < 6) ? (const float4*)(Wih + jj * 192 + 32 * e)
                               : (const float4*)(Whh + jj * H2_ + 32 * (e - 6));
    w0 = wa[0];  w1 = wa[1];  w2 = wa[2];  w3 = wa[3];
    w4 = wa[4];  w5 = wa[5];  w6 = wa[6];  w7 = wa[7];
    const float4* wb = (e < 6) ? (const float4*)(Wih + (jj + 128) * 192 + 32 * e)
                               : (const float4*)(Whh + (jj + 128) * H2_ + 32 * (e - 6));
    w8  = wb[0]; w9  = wb[1]; w10 = wb[2]; w11 = wb[3];
    w12 = wb[4]; w13 = wb[5]; w14 = wb[6]; w15 = wb[7];
  }

  const int uj = tid & 63;                       // updaters: tid < 256
  const int ub = (tid >> 6) & 3;
  const float bias_i = bih[uj      ] + bhh[uj      ];
  const float bias_f = bih[uj +  64] + bhh[uj +  64];
  const float bias_g = bih[uj + 128] + bhh[uj + 128];
  const float bias_o = bih[uj + 192] + bhh[uj + 192];
  float c_state = 0.0f;

  for (int i = tid; i < 4 * 256; i += 1024) (&hx[0][0])[i] = 0.0f;
  __syncthreads();
  const int pb = tid / 96;                       // h1 stagers: tid < 384
  const int pj = tid - pb * 96;
  if (tid < 384) {
    *(float2*)&hx[pb][pj * 2] =
        *(const float2*)&g_h1[((size_t)(b0 + pb) * T_ + 0) * 192 + pj * 2];
  }
  __syncthreads();

  const int eoff = e * 8;
  const float4* hx4 = (const float4*)(&hx[0][0]);

  for (int s = 0; s < T_; ++s) {
    float2 pre = make_float2(0.0f, 0.0f);
    if (tid < 384 && s + 1 < T_) {
      pre = *(const float2*)&g_h1[((size_t)(b0 + pb) * T_ + (s + 1)) * 192 + pj * 2];
    }
    float accA0=0.f, accA1=0.f, accA2=0.f, accA3=0.f;
    float accB0=0.f, accB1=0.f, accB2=0.f, accB3=0.f;
#define FB2(i, k) {                                                           \
    float4 v0 = hx4[0*64 + eoff + i]; float4 v1 = hx4[1*64 + eoff + i];       \
    float4 v2 = hx4[2*64 + eoff + i]; float4 v3 = hx4[3*64 + eoff + i];       \
    FMAROW(accA0, w##i, v0) FMAROW(accB0, w##k, v0)                           \
    FMAROW(accA1, w##i, v1) FMAROW(accB1, w##k, v1)                           \
    FMAROW(accA2, w##i, v2) FMAROW(accB2, w##k, v2)                           \
    FMAROW(accA3, w##i, v3) FMAROW(accB3, w##k, v3) }
    FB2(0,8) FB2(1,9) FB2(2,10) FB2(3,11)
    FB2(4,12) FB2(5,13) FB2(6,14) FB2(7,15)
#undef FB2
    {
      const int ga = jj * 33 + e;                // lanes: jj consecutive -> 2-way
      gbuf[ga +  0] = accA0; gbuf[ga +  8] = accA1;
      gbuf[ga + 16] = accA2; gbuf[ga + 24] = accA3;
      const int gbB = (jj + 128) * 33 + e;
      gbuf[gbB +  0] = accB0; gbuf[gbB +  8] = accB1;
      gbuf[gbB + 16] = accB2; gbuf[gbB + 24] = accB3;
    }
    BAR_LGKM();
    if (tid < 384 && s + 1 < T_) *(float2*)&hx[pb][pj * 2] = pre;
    if (tid < 256) {
      const int ro = ub * 8;
      float gi = bias_i, gf = bias_f, gg = bias_g, go = bias_o;
#pragma unroll
      for (int ee = 0; ee < 8; ++ee) {
        gi += gbuf[(uj      ) * 33 + ro + ee];
        gf += gbuf[(uj +  64) * 33 + ro + ee];
        gg += gbuf[(uj + 128) * 33 + ro + ee];
        go += gbuf[(uj + 192) * 33 + ro + ee];
      }
      float iv = fast_sigmoid(gi), fv = fast_sigmoid(gf), ov = fast_sigmoid(go);
      c_state = fv * c_state + iv * fast_tanh(gg);
      float h = ov * fast_tanh(c_state);
      hx[ub][192 + uj] = h;
      if (s == T_ - 1) g_h2f[(b0 + ub) * H2_ + uj] = h;
    }
    BAR_LGKM();
  }
}

// ---------------------------------------------------------------------------
// Tail: layer-2 backward (ONE step from zero state on h1[:,T-1,:]) + dense
// head. grid 128 x 256 threads, 8 batch/block. (negligible runtime)
// ---------------------------------------------------------------------------
__global__ __launch_bounds__(256)
void tail_kernel(const float* __restrict__ Wih, const float* __restrict__ bih,
                 const float* __restrict__ bhh,
                 const float* __restrict__ W1, const float* __restrict__ b1,
                 const float* __restrict__ W2, const float* __restrict__ b2,
                 float* __restrict__ out)
{
  const int tid = threadIdx.x;
  const int b0  = blockIdx.x * 8;

  __shared__ __align__(16) float hl[8][192];    // h1 at t = T-1
  __shared__ float gb[G2_ * 9];
  __shared__ __align__(16) float last[8][128];  // [h2f | h2b]
  __shared__ float db[8][32];

  for (int i = tid; i < 8 * 96; i += 256) {
    int bb = i / 96, jj = i - (i / 96) * 96;
    *(float2*)&hl[bb][jj * 2] =
        *(const float2*)&g_h1[((size_t)(b0 + bb) * T_ + (T_ - 1)) * 192 + jj * 2];
  }
  for (int i = tid; i < 8 * 64; i += 256) {
    int bb = i >> 6, jj = i & 63;
    last[bb][jj] = g_h2f[(b0 + bb) * H2_ + jj];
  }
  __syncthreads();

  {
    const int gg_ = tid;
    const float* wr = Wih + gg_ * 192;
    const float bias = bih[gg_] + bhh[gg_];
    float acc[8];
#pragma unroll
    for (int b = 0; b < 8; ++b) acc[b] = bias;
#pragma unroll 4
    for (int qq = 0; qq < 48; ++qq) {
      float4 wv = *(const float4*)&wr[qq * 4];
#pragma unroll
      for (int b = 0; b < 8; ++b) {
        float4 v = *(const float4*)&hl[b][qq * 4];
        acc[b] = fmaf(wv.x, v.x, acc[b]);
        acc[b] = fmaf(wv.y, v.y, acc[b]);
        acc[b] = fmaf(wv.z, v.z, acc[b]);
        acc[b] = fmaf(wv.w, v.w, acc[b]);
      }
    }
#pragma unroll
    for (int b = 0; b < 8; ++b) gb[gg_ * 9 + b] = acc[b];
  }
  __syncthreads();

  for (int p = tid; p < 512; p += 256) {
    int jj = p & 63, bb = p >> 6;
    float gi = gb[(jj      ) * 9 + bb];
    float gg = gb[(jj + 128) * 9 + bb];
    float go = gb[(jj + 192) * 9 + bb];
    float c  = fast_sigmoid(gi) * fast_tanh(gg);
    float h  = fast_sigmoid(go) * fast_tanh(c);
    last[bb][64 + jj] = h;
  }
  __syncthreads();

  {
    int uu = tid & 31, bb = tid >> 5;
    const float* wr1 = W1 + uu * 128;
    float a = b1[uu];
#pragma unroll
    for (int qq = 0; qq < 32; ++qq) {
      float4 wv = *(const float4*)&wr1[qq * 4];
      float4 v  = *(const float4*)&last[bb][qq * 4];
      a = fmaf(wv.x, v.x, a); a = fmaf(wv.y, v.y, a);
      a = fmaf(wv.z, v.z, a); a = fmaf(wv.w, v.w, a);
    }
    db[bb][uu] = fmaxf(a, 0.0f);
  }
  __syncthreads();

  if (tid < 8) {
    float a = b2[0];
#pragma unroll
    for (int u2 = 0; u2 < 32; ++u2) a = fmaf(db[tid][u2], W2[u2], a);
    out[b0 + tid] = a;
  }
}

extern "C" void kernel_launch(void* const* d_in, const int* in_sizes, int n_in,
                              void* d_out, int out_size, void* d_ws, size_t ws_size,
                              hipStream_t stream)
{
  const float* x     = (const float*)d_in[0];
  const float* Wih1f = (const float*)d_in[1];
  const float* Whh1f = (const float*)d_in[2];
  const float* bih1f = (const float*)d_in[3];
  const float* bhh1f = (const float*)d_in[4];
  const float* Wih1b = (const float*)d_in[5];
  const float* Whh1b = (const float*)d_in[6];
  const float* bih1b = (const float*)d_in[7];
  const float* bhh1b = (const float*)d_in[8];
  const float* Wih2f = (const float*)d_in[9];
  const float* Whh2f = (const float*)d_in[10];
  const float* bih2f = (const float*)d_in[11];
  const float* bhh2f = (const float*)d_in[12];
  const float* Wih2b = (const float*)d_in[13];
  /* Whh2b (d_in[14]) unused: layer-2 backward at t=T-1 is one step from h=0 */
  const float* bih2b = (const float*)d_in[15];
  const float* bhh2b = (const float*)d_in[16];
  const float* W1    = (const float*)d_in[17];
  const float* b1    = (const float*)d_in[18];
  const float* W2    = (const float*)d_in[19];
  const float* b2    = (const float*)d_in[20];

  (void)d_ws; (void)ws_size; (void)in_sizes; (void)n_in; (void)out_size;

  lstm1_kernel<<<dim3(128, 2), 768, 0, stream>>>(
      x, Wih1f, Whh1f, bih1f, bhh1f, Wih1b, Whh1b, bih1b, bhh1b);
  lstm2f_kernel<<<256, 1024, 0, stream>>>(
      Wih2f, Whh2f, bih2f, bhh2f);
  tail_kernel<<<128, 256, 0, stream>>>(
      Wih2b, bih2b, bhh2b, W1, b1, W2, b2, (float*)d_out);
}